// Round 5
// baseline (133.055 us; speedup 1.0000x reference)
//
#include <hip/hip_runtime.h>

#define NDIM 1024
#define BDIM 128
#define NBANDS 32    // 32 row-bands of 32 rows

// One kernel, one dispatch, no workspace, no atomics, no memset.
// Block bid owns outputs b0=2*bid, b1=2*bid+1 and computes the FULL
// upper-triangle sum for both (plain stores overwrite poisoned out):
//   out[b] = sum_i [ (1-v_bi)*R_i + (2*v_bi-1)*z_bi ]
//   R_i = sum_{j>=i} W_ij          (b-independent, shared by b0/b1)
//   z_bi = sum_{j>=i} W_ij v_bj
// Redundant W reads (64 blocks x 2.1 MB triu = 134 MB) are L2-resident
// (triu fits in each XCD's 4 MB L2) ~ 3.9 us aggregate, hidden under the
// ~6 us of VALU work. This removes the 25-30 us cross-block reduction
// cost (dispatch gaps / atomic chains) that dominated rounds 0-4.
//
// Thread mapping (256 thr): jq=tid&7 (col quad), dup=(tid>>3)&3 (one of 4
// concurrent 32-col tiles), i4=tid>>5 (row group; 4 rows each). Per wave
// W-load: 2 rows x 512B contiguous -> coalesced. LDS v reads: 2 b128 per
// 48 VALU ops -> LDS pipe far subcritical (the failure mode of per-b
// designs with scalar v reads).
__global__ __launch_bounds__(256) void potts_oneb(
    const float* __restrict__ V,   // [128][1024]
    const float* __restrict__ W,   // [1024][1024]
    float* __restrict__ out)       // [128]
{
    const int b0 = 2 * blockIdx.x, b1 = b0 + 1;

    __shared__ float vA[NDIM];
    __shared__ float vB[NDIM];
    __shared__ float redA[4], redB[4];

    const int tid = threadIdx.x;

    // stage both V rows (1024 floats each = 256 float4 = one per thread)
    {
        const float4 a = ((const float4*)(V + (size_t)b0 * NDIM))[tid];
        const float4 b = ((const float4*)(V + (size_t)b1 * NDIM))[tid];
        ((float4*)vA)[tid] = a;
        ((float4*)vB)[tid] = b;
    }
    __syncthreads();

    const int jq  = tid & 7;          // col quad within a 32-col tile
    const int dup = (tid >> 3) & 3;   // which of 4 concurrent tiles
    const int i4  = tid >> 5;         // row group [0,8): rows 4*i4..+4

    float accA = 0.0f, accB = 0.0f;

    for (int ib = 0; ib < NBANDS; ++ib) {
        const int I0 = ib * 32;
        const int r0 = I0 + 4 * i4;   // first of this thread's 4 rows
        float racc[4] = {0.f, 0.f, 0.f, 0.f};
        float zA[4]   = {0.f, 0.f, 0.f, 0.f};
        float zB[4]   = {0.f, 0.f, 0.f, 0.f};

        const int nt = NBANDS - ib;          // J-tiles in this band (triu)
        const int ns = (nt + 3) >> 2;        // steps of 4 tiles
        for (int s = 0; s < ns; ++s) {
            const int tile = ib + 4 * s + dup;
            if (tile < NBANDS) {
                const int c0 = tile * 32 + jq * 4;          // first col
                const float4 va = *(const float4*)(vA + c0);
                const float4 vb = *(const float4*)(vB + c0);
                const bool dm = (tile == ib);               // diagonal tile
#pragma unroll
                for (int r = 0; r < 4; ++r) {
                    const int row = r0 + r;
                    float4 wq = *(const float4*)(W + (size_t)row * NDIM + c0);
                    if (dm) {                 // triu: keep col >= row
                        const int lr = 4 * i4 + r;   // row within tile
                        const int lc = jq * 4;       // col within tile
                        if (lc + 0 < lr) wq.x = 0.0f;
                        if (lc + 1 < lr) wq.y = 0.0f;
                        if (lc + 2 < lr) wq.z = 0.0f;
                        if (lc + 3 < lr) wq.w = 0.0f;
                    }
                    racc[r] += (wq.x + wq.y) + (wq.z + wq.w);
                    zA[r] = fmaf(wq.x, va.x, zA[r]);
                    zA[r] = fmaf(wq.y, va.y, zA[r]);
                    zA[r] = fmaf(wq.z, va.z, zA[r]);
                    zA[r] = fmaf(wq.w, va.w, zA[r]);
                    zB[r] = fmaf(wq.x, vb.x, zB[r]);
                    zB[r] = fmaf(wq.y, vb.y, zB[r]);
                    zB[r] = fmaf(wq.z, vb.z, zB[r]);
                    zB[r] = fmaf(wq.w, vb.w, zB[r]);
                }
            }
        }

        // band epilogue: weight per-row partials by this b's v_i
#pragma unroll
        for (int r = 0; r < 4; ++r) {
            const float yA = vA[r0 + r];
            const float yB = vB[r0 + r];
            accA = fmaf(1.0f - yA, racc[r], accA);
            accA = fmaf(2.0f * yA - 1.0f, zA[r], accA);
            accB = fmaf(1.0f - yB, racc[r], accB);
            accB = fmaf(2.0f * yB - 1.0f, zB[r], accB);
        }
    }

    // reduce 256 threads -> 2 scalars (wave shfl, then 4-wave LDS fold)
#pragma unroll
    for (int off = 32; off > 0; off >>= 1) {
        accA += __shfl_down(accA, off);
        accB += __shfl_down(accB, off);
    }
    const int w = tid >> 6, l = tid & 63;
    if (l == 0) { redA[w] = accA; redB[w] = accB; }
    __syncthreads();
    if (tid == 0) out[b0] = (redA[0] + redA[1]) + (redA[2] + redA[3]);
    if (tid == 1) out[b1] = (redB[0] + redB[1]) + (redB[2] + redB[3]);
}

extern "C" void kernel_launch(void* const* d_in, const int* in_sizes, int n_in,
                              void* d_out, int out_size, void* d_ws, size_t ws_size,
                              hipStream_t stream) {
    const float* V = (const float*)d_in[0];
    const float* W = (const float*)d_in[1];
    float* out = (float*)d_out;
    (void)d_ws; (void)ws_size;

    potts_oneb<<<dim3(BDIM / 2), dim3(256), 0, stream>>>(V, W, out);
}

// Round 6
// 71.700 us; speedup vs baseline: 1.8557x; 1.8557x over previous
//
#include <hip/hip_runtime.h>
#include <math.h>

#define NDIM 1024
#define BDIM 128
#define TS 32
#define NT (NDIM / TS)                 // 32
#define NTILES (NT * (NT + 1) / 2)     // 528 upper-tri tiles

// Two-dispatch plain-store structure (measured best: R0 tail 24us; every
// fusion variant lost: fence election +43us, same-address atomics +13us,
// per-output redundant compute +57us; gaps measured ~0).
//
// Main: one block per upper-tri 32x32 tile.
//   contribution(b) = (1-v_bi)*RS_i + (2*v_bi-1)*z_bi per masked row i,
//   RS_i = masked row sum, z_bi = sum_j W_ij v_bj. 1 MAC per W element.
// Latency plan: caches are fully evicted each iteration by the 256MB
// poison fill, so first-touch is HBM (~900cy). Issue ALL 13 global float4
// loads back-to-back at the top (1 W quad + 4 vj staging + 4 direct vi),
// one round-trip covers everything. vi4 LDS array dropped (35->19KB LDS).
// W in FMA loop is wave-uniform L1-hot broadcast (R1: == LDS-W perf).
// Partials stored TRANSPOSED partial[b][t] (scattered 4B stores, fire &
// forget) so the red kernel reads contiguous rows.
__global__ __launch_bounds__(256) void potts_main(
    const float* __restrict__ V,      // [128][1024]
    const float* __restrict__ W,      // [1024][1024]
    float* __restrict__ partial)      // [BDIM][NTILES]
{
    const int t = blockIdx.x;
    // closed-form upper-tri tile index (verified rounds 1-5: same absmax)
    const int u = NTILES - 1 - t;
    int kk = (int)(0.5f * (sqrtf((float)(8 * u + 1)) - 1.0f));
    if (kk * (kk + 1) / 2 > u) --kk;
    if ((kk + 1) * (kk + 2) / 2 <= u) ++kk;
    const int ti = NT - 1 - kk;
    const int tj = NT - 1 - (u - kk * (kk + 1) / 2);
    const int I0 = ti * TS, J0 = tj * TS;
    const bool diag = (ti == tj);

    __shared__ float4 vj4[BDIM][8];     // V[b][J0+4*j4..+4] at column j4^(b&7)
    __shared__ float rs[TS];            // masked row sums
    __shared__ float red[4][BDIM];

    const int tid = threadIdx.x;
    const int w = tid >> 6;
    const int l = tid & 63;
    const int l7 = l & 7;

    // ================= issue ALL global loads up front =================
    const int r = tid >> 3, c4 = (tid & 7) * 4;
    float4 w4 = *(const float4*)(W + (size_t)(I0 + r) * NDIM + (J0 + c4));

    float4 sv0 = *(const float4*)(V + (size_t)((tid + 0 * 256) >> 3) * NDIM + (J0 + 4 * ((tid + 0 * 256) & 7)));
    float4 sv1 = *(const float4*)(V + (size_t)((tid + 1 * 256) >> 3) * NDIM + (J0 + 4 * ((tid + 1 * 256) & 7)));
    float4 sv2 = *(const float4*)(V + (size_t)((tid + 2 * 256) >> 3) * NDIM + (J0 + 4 * ((tid + 2 * 256) & 7)));
    float4 sv3 = *(const float4*)(V + (size_t)((tid + 3 * 256) >> 3) * NDIM + (J0 + 4 * ((tid + 3 * 256) & 7)));

    // direct per-lane vi: V[b][I0+8w .. +8] for b0=l, b1=l+64
    const float4 p0 = *(const float4*)(V + (size_t)l * NDIM + (I0 + 8 * w));
    const float4 q0 = *(const float4*)(V + (size_t)l * NDIM + (I0 + 8 * w + 4));
    const float4 p1 = *(const float4*)(V + (size_t)(l + 64) * NDIM + (I0 + 8 * w));
    const float4 q1 = *(const float4*)(V + (size_t)(l + 64) * NDIM + (I0 + 8 * w + 4));

    // ================= masked row sums from w4 =========================
    if (diag) {                      // triu: keep j >= i
        if (c4 + 0 < r) w4.x = 0.0f;
        if (c4 + 1 < r) w4.y = 0.0f;
        if (c4 + 2 < r) w4.z = 0.0f;
        if (c4 + 3 < r) w4.w = 0.0f;
    }
    {
        float rsum = (w4.x + w4.y) + (w4.z + w4.w);
        rsum += __shfl_xor(rsum, 1);
        rsum += __shfl_xor(rsum, 2);
        rsum += __shfl_xor(rsum, 4);
        if ((tid & 7) == 0) rs[r] = rsum;
    }

    // ================= stage vj (swizzled float4 columns) ==============
    {
        int fid, b, j4;
        fid = tid + 0 * 256; b = fid >> 3; j4 = fid & 7; vj4[b][j4 ^ (b & 7)] = sv0;
        fid = tid + 1 * 256; b = fid >> 3; j4 = fid & 7; vj4[b][j4 ^ (b & 7)] = sv1;
        fid = tid + 2 * 256; b = fid >> 3; j4 = fid & 7; vj4[b][j4 ^ (b & 7)] = sv2;
        fid = tid + 3 * 256; b = fid >> 3; j4 = fid & 7; vj4[b][j4 ^ (b & 7)] = sv3;
    }
    __syncthreads();

    // ---- per-lane vj registers (b128 reads, swizzle-matched)
    float vj0[TS], vj1[TS];
#pragma unroll
    for (int j4 = 0; j4 < 8; ++j4) {
        const int g = j4 ^ l7;
        const float4 a = vj4[l][g];
        vj0[4*j4+0] = a.x; vj0[4*j4+1] = a.y;
        vj0[4*j4+2] = a.z; vj0[4*j4+3] = a.w;
        const float4 c = vj4[l + 64][g];
        vj1[4*j4+0] = c.x; vj1[4*j4+1] = c.y;
        vj1[4*j4+2] = c.z; vj1[4*j4+3] = c.w;
    }
    // ---- vi registers from the up-front direct loads
    float vi0[8], vi1[8];
    vi0[0]=p0.x; vi0[1]=p0.y; vi0[2]=p0.z; vi0[3]=p0.w;
    vi0[4]=q0.x; vi0[5]=q0.y; vi0[6]=q0.z; vi0[7]=q0.w;
    vi1[0]=p1.x; vi1[1]=p1.y; vi1[2]=p1.z; vi1[3]=p1.w;
    vi1[4]=q1.x; vi1[5]=q1.y; vi1[6]=q1.z; vi1[7]=q1.w;

    float acc0 = 0.0f, acc1 = 0.0f;
#pragma unroll
    for (int k = 0; k < 8; ++k) {
        const int i = 8 * w + k;
        const float* __restrict__ wrow = W + (size_t)(I0 + i) * NDIM + J0;
        float za0 = 0.f, zb0 = 0.f, za1 = 0.f, zb1 = 0.f;
#pragma unroll
        for (int j4 = 0; j4 < 8; j4 += 2) {
            float4 wa = *(const float4*)(wrow + 4 * j4);       // L1-hot broadcast
            float4 wb = *(const float4*)(wrow + 4 * j4 + 4);
            if (diag) {                  // triu mask, per-k uniform
                if (4*j4 + 0 < i) wa.x = 0.0f;
                if (4*j4 + 1 < i) wa.y = 0.0f;
                if (4*j4 + 2 < i) wa.z = 0.0f;
                if (4*j4 + 3 < i) wa.w = 0.0f;
                if (4*j4 + 4 < i) wb.x = 0.0f;
                if (4*j4 + 5 < i) wb.y = 0.0f;
                if (4*j4 + 6 < i) wb.z = 0.0f;
                if (4*j4 + 7 < i) wb.w = 0.0f;
            }
            za0 = fmaf(wa.x, vj0[4*j4+0], za0);
            za0 = fmaf(wa.y, vj0[4*j4+1], za0);
            za0 = fmaf(wa.z, vj0[4*j4+2], za0);
            za0 = fmaf(wa.w, vj0[4*j4+3], za0);
            za1 = fmaf(wa.x, vj1[4*j4+0], za1);
            za1 = fmaf(wa.y, vj1[4*j4+1], za1);
            za1 = fmaf(wa.z, vj1[4*j4+2], za1);
            za1 = fmaf(wa.w, vj1[4*j4+3], za1);
            zb0 = fmaf(wb.x, vj0[4*j4+4], zb0);
            zb0 = fmaf(wb.y, vj0[4*j4+5], zb0);
            zb0 = fmaf(wb.z, vj0[4*j4+6], zb0);
            zb0 = fmaf(wb.w, vj0[4*j4+7], zb0);
            zb1 = fmaf(wb.x, vj1[4*j4+4], zb1);
            zb1 = fmaf(wb.y, vj1[4*j4+5], zb1);
            zb1 = fmaf(wb.z, vj1[4*j4+6], zb1);
            zb1 = fmaf(wb.w, vj1[4*j4+7], zb1);
        }
        const float y0 = vi0[k], y1 = vi1[k];
        const float rsk = rs[i];
        acc0 = fmaf(1.0f - y0, rsk, acc0);
        acc0 = fmaf(2.0f * y0 - 1.0f, za0 + zb0, acc0);
        acc1 = fmaf(1.0f - y1, rsk, acc1);
        acc1 = fmaf(2.0f * y1 - 1.0f, za1 + zb1, acc1);
    }

    // ---- block reduce, then TRANSPOSED plain store partial[b][t]
    red[w][l] = acc0;
    red[w][l + 64] = acc1;
    __syncthreads();
    if (tid < BDIM) {
        partial[(size_t)tid * NTILES + t] =
            (red[0][tid] + red[1][tid]) + (red[2][tid] + red[3][tid]);
    }
}

// ---- reduce: block b reads its CONTIGUOUS 528-float row, ~2-3 loads/thread
__global__ __launch_bounds__(256) void potts_red(
    const float* __restrict__ partial, float* __restrict__ out)
{
    const int b = blockIdx.x;
    const int tid = threadIdx.x;
    const float* __restrict__ row = partial + (size_t)b * NTILES;
    float a = row[tid] + row[tid + 256];
    if (tid < NTILES - 512) a += row[tid + 512];
#pragma unroll
    for (int off = 32; off > 0; off >>= 1)
        a += __shfl_down(a, off);
    __shared__ float rr[4];
    if ((tid & 63) == 0) rr[tid >> 6] = a;
    __syncthreads();
    if (tid == 0) out[b] = (rr[0] + rr[1]) + (rr[2] + rr[3]);
}

extern "C" void kernel_launch(void* const* d_in, const int* in_sizes, int n_in,
                              void* d_out, int out_size, void* d_ws, size_t ws_size,
                              hipStream_t stream) {
    const float* V = (const float*)d_in[0];
    const float* W = (const float*)d_in[1];
    float* out = (float*)d_out;
    float* partial = (float*)d_ws;            // 128*528*4 = 270336 B

    potts_main<<<dim3(NTILES), dim3(256), 0, stream>>>(V, W, partial);
    potts_red<<<dim3(BDIM), dim3(256), 0, stream>>>(partial, out);
}

// Round 7
// 64.452 us; speedup vs baseline: 2.0644x; 1.1125x over previous
//
#include <hip/hip_runtime.h>
#include <math.h>

#define NDIM 1024
#define BDIM 128
#define TS 32
#define NT (NDIM / TS)                 // 32
#define NTILES (NT * (NT + 1) / 2)     // 528 upper-tri tiles
#define NHALF (NTILES * 2)             // 1056 half-tiles (16 rows x 32 cols)
#define R1B 16                         // red1 block count
#define ROWS_PER_R1 (NHALF / R1B)      // 66

// Three-dispatch plain-store structure. R0 (2-dispatch, 65.1us) is the
// measured best; R6 showed uncoalesced vi loads + scattered stores cost
// ~6us -> kernels are latency-bound, coalescing is king. Main's work
// content is ~2-3us but it ran ~18-20us at 2 blocks/CU: unhidden cold
// latency. Fix: half-tiles -> 1056 blocks x 128 thr (2 waves), halving
// per-block critical path and doubling independent resident blocks.
// All access patterns are R0-proven: coalesced float4 global loads,
// 130-padded transposed LDS (2-way free banks), wt[.][36] broadcast rows,
// coalesced partial[t2][b] stores.
__global__ __launch_bounds__(128) void potts_main(
    const float* __restrict__ V,      // [128][1024]
    const float* __restrict__ W,      // [1024][1024]
    float* __restrict__ partial)      // [NHALF][BDIM]
{
    const int t2 = blockIdx.x;
    const int t = t2 >> 1, half = t2 & 1;
    // closed-form upper-tri tile index (verified rounds 1-6)
    const int u = NTILES - 1 - t;
    int kk = (int)(0.5f * (sqrtf((float)(8 * u + 1)) - 1.0f));
    if (kk * (kk + 1) / 2 > u) --kk;
    if ((kk + 1) * (kk + 2) / 2 <= u) ++kk;
    const int ti = NT - 1 - kk;
    const int tj = NT - 1 - (u - kk * (kk + 1) / 2);
    const int rbase = 16 * half;          // local-row offset of this half
    const int I0h = ti * TS + rbase;      // absolute first row of half
    const int J0 = tj * TS;
    const bool diag = (ti == tj);

    __shared__ float wt[16][36];        // masked W half-tile, broadcast reads
    __shared__ float rs[16];            // masked row sums
    __shared__ float vjt[TS][130];      // V[:,J0+j] transposed [j][b]
    __shared__ float vit[16][130];      // V[:,I0h+i] transposed [i][b]
    __shared__ float red[2][BDIM];

    const int tid = threadIdx.x;        // 0..127
    const int w = tid >> 6;             // wave 0/1 -> rows 8w..8w+8
    const int l = tid & 63;

    // ---- W half-tile: 1 float4/thread (coalesced), mask, rowsum, stage
    {
        const int r = tid >> 3, c4 = (tid & 7) * 4;      // r: 0..15
        float4 w4 = *(const float4*)(W + (size_t)(I0h + r) * NDIM + (J0 + c4));
        if (diag) {                      // triu: keep local col >= local row
            const int lr = rbase + r;
            if (c4 + 0 < lr) w4.x = 0.0f;
            if (c4 + 1 < lr) w4.y = 0.0f;
            if (c4 + 2 < lr) w4.z = 0.0f;
            if (c4 + 3 < lr) w4.w = 0.0f;
        }
        *(float4*)(&wt[r][c4]) = w4;
        float rsum = (w4.x + w4.y) + (w4.z + w4.w);
        rsum += __shfl_xor(rsum, 1);
        rsum += __shfl_xor(rsum, 2);
        rsum += __shfl_xor(rsum, 4);
        if ((tid & 7) == 0) rs[r] = rsum;
    }

    // ---- stage vj: V[:,J0..J0+32] transposed (4096 floats, 8 iters)
#pragma unroll
    for (int it = 0; it < 8; ++it) {
        const int fid = tid + 128 * it;       // 0..1023
        const int b = fid >> 3, c4 = (fid & 7) * 4;
        const float4 a = *(const float4*)(V + (size_t)b * NDIM + (J0 + c4));
        vjt[c4 + 0][b] = a.x; vjt[c4 + 1][b] = a.y;
        vjt[c4 + 2][b] = a.z; vjt[c4 + 3][b] = a.w;
    }
    // ---- stage vi: V[:,I0h..I0h+16] transposed (2048 floats, 4 iters)
#pragma unroll
    for (int it = 0; it < 4; ++it) {
        const int fid = tid + 128 * it;       // 0..511
        const int b = fid >> 2, c4 = (fid & 3) * 4;
        const float4 a = *(const float4*)(V + (size_t)b * NDIM + (I0h + c4));
        vit[c4 + 0][b] = a.x; vit[c4 + 1][b] = a.y;
        vit[c4 + 2][b] = a.z; vit[c4 + 3][b] = a.w;
    }
    __syncthreads();

    // ---- per-lane vj registers (2-way-free LDS reads)
    float vj0[TS], vj1[TS];
#pragma unroll
    for (int j = 0; j < TS; ++j) {
        vj0[j] = vjt[j][l];
        vj1[j] = vjt[j][l + 64];
    }

    float acc0 = 0.0f, acc1 = 0.0f;
#pragma unroll
    for (int k = 0; k < 8; ++k) {
        const int il = 8 * w + k;             // 0..15 within half
        const float vi0 = vit[il][l], vi1 = vit[il][l + 64];
        const float* wrow = &wt[il][0];
        float za0 = 0.f, zb0 = 0.f, za1 = 0.f, zb1 = 0.f;
#pragma unroll
        for (int j4 = 0; j4 < 8; j4 += 2) {
            const float4 wa = *(const float4*)(wrow + 4 * j4);     // broadcast
            const float4 wb = *(const float4*)(wrow + 4 * j4 + 4); // broadcast
            za0 = fmaf(wa.x, vj0[4 * j4 + 0], za0);
            za0 = fmaf(wa.y, vj0[4 * j4 + 1], za0);
            za0 = fmaf(wa.z, vj0[4 * j4 + 2], za0);
            za0 = fmaf(wa.w, vj0[4 * j4 + 3], za0);
            za1 = fmaf(wa.x, vj1[4 * j4 + 0], za1);
            za1 = fmaf(wa.y, vj1[4 * j4 + 1], za1);
            za1 = fmaf(wa.z, vj1[4 * j4 + 2], za1);
            za1 = fmaf(wa.w, vj1[4 * j4 + 3], za1);
            zb0 = fmaf(wb.x, vj0[4 * j4 + 4], zb0);
            zb0 = fmaf(wb.y, vj0[4 * j4 + 5], zb0);
            zb0 = fmaf(wb.z, vj0[4 * j4 + 6], zb0);
            zb0 = fmaf(wb.w, vj0[4 * j4 + 7], zb0);
            zb1 = fmaf(wb.x, vj1[4 * j4 + 4], zb1);
            zb1 = fmaf(wb.y, vj1[4 * j4 + 5], zb1);
            zb1 = fmaf(wb.z, vj1[4 * j4 + 6], zb1);
            zb1 = fmaf(wb.w, vj1[4 * j4 + 7], zb1);
        }
        const float rsk = rs[il];
        acc0 = fmaf(1.0f - vi0, rsk, acc0);
        acc0 = fmaf(2.0f * vi0 - 1.0f, za0 + zb0, acc0);
        acc1 = fmaf(1.0f - vi1, rsk, acc1);
        acc1 = fmaf(2.0f * vi1 - 1.0f, za1 + zb1, acc1);
    }

    // ---- block reduce (2 waves), coalesced plain store partial[t2][b]
    red[w][l] = acc0;
    red[w][l + 64] = acc1;
    __syncthreads();
    if (tid < BDIM) {
        partial[(size_t)t2 * BDIM + tid] = red[0][tid] + red[1][tid];
    }
}

// ---- red1: 16 blocks, each sums 66 contiguous partial rows (coalesced)
__global__ __launch_bounds__(256) void potts_red1(
    const float* __restrict__ partial, float* __restrict__ ws2)
{
    const int g = blockIdx.x;            // 0..15
    const int tid = threadIdx.x;
    const int b = tid & 127, h = tid >> 7;
    const float* __restrict__ base = partial + (size_t)g * ROWS_PER_R1 * BDIM;
    float a = 0.0f;
#pragma unroll
    for (int kx = 0; kx < ROWS_PER_R1 / 2; ++kx)     // 33 coalesced loads
        a += base[(size_t)(2 * kx + h) * BDIM + b];
    __shared__ float s[256];
    s[tid] = a;
    __syncthreads();
    if (tid < BDIM) ws2[g * BDIM + tid] = s[tid] + s[tid + BDIM];
}

// ---- red2: 1 block folds 16 rows -> out[128] (coalesced)
__global__ __launch_bounds__(256) void potts_red2(
    const float* __restrict__ ws2, float* __restrict__ out)
{
    const int tid = threadIdx.x;
    const int b = tid & 127, h = tid >> 7;
    float a = 0.0f;
#pragma unroll
    for (int g = 0; g < R1B / 2; ++g)                // 8 coalesced loads
        a += ws2[(2 * g + h) * BDIM + b];
    __shared__ float s[256];
    s[tid] = a;
    __syncthreads();
    if (tid < BDIM) out[tid] = s[tid] + s[tid + BDIM];
}

extern "C" void kernel_launch(void* const* d_in, const int* in_sizes, int n_in,
                              void* d_out, int out_size, void* d_ws, size_t ws_size,
                              hipStream_t stream) {
    const float* V = (const float*)d_in[0];
    const float* W = (const float*)d_in[1];
    float* out = (float*)d_out;
    float* partial = (float*)d_ws;                    // NHALF*128*4 = 540672 B
    float* ws2 = partial + (size_t)NHALF * BDIM;      // +16*128*4 = 8 KB

    potts_main<<<dim3(NHALF), dim3(128), 0, stream>>>(V, W, partial);
    potts_red1<<<dim3(R1B), dim3(256), 0, stream>>>(partial, ws2);
    potts_red2<<<dim3(1), dim3(256), 0, stream>>>(ws2, out);
}